// Round 4
// baseline (380.999 us; speedup 1.0000x reference)
//
#include <hip/hip_runtime.h>
#include <stdint.h>

// ConvolutionN: B=64, C=64, H=W=128, K=7, PAD=3, one output channel, fp32.
// v4: MFMA row-decomposition (as v3) with restructured single-barrier K-loop:
//   - one lgkm-only barrier per row (asm "s_waitcnt lgkmcnt(0); s_barrier"):
//     global prefetch for row r+2 stays in flight across the barrier
//   - bank-safe staging writes (cgrp-fastest: lanes 0-7 -> banks 0,4,...,28)
//   - drain of out-row r-3 moved after the same barrier (no second barrier)
// Race analysis (wave program order + 1 barrier/iter):
//   xlds[(it+1)&1] written pre-barrier(it), read post-barrier(it) in iter it+1;
//   prior readers of that buffer finished pre-barrier(it-1). Ring slot it&7
//   written pre-barrier(it), last read post-barrier at iter it+6, rewritten
//   iter it+8. All safe.

typedef short bf16x8 __attribute__((ext_vector_type(8)));
typedef float f32x4 __attribute__((ext_vector_type(4)));

#define HB    16
#define NR    22            // HB + 6 P-rows per band
#define XS    36            // dwords per col slot (64 bf16 = 32 dw + 4 pad); 36%32=4 -> stride-4 banks
#define XCOLS 134           // cols -3..130 stored at +3
#define XBUF  (XCOLS * XS)
#define RROW  132           // ring row stride (dw)
#define RING_DW (8 * 7 * RROW)

__device__ __forceinline__ uint32_t pk2bf(float a, float b) {
    // low16 = bf16_rne(a), high16 = bf16_rne(b)
    uint32_t ua = __builtin_bit_cast(uint32_t, a);
    uint32_t ub = __builtin_bit_cast(uint32_t, b);
    ua += 0x7FFFu + ((ua >> 16) & 1u);
    ub += 0x7FFFu + ((ub >> 16) & 1u);
    return (ua >> 16) | (ub & 0xFFFF0000u);
}

// Barrier that drains LDS ops only — leaves global loads in flight (vmcnt
// untouched). This is the CK/AITER pattern; __syncthreads would emit
// s_waitcnt vmcnt(0) and expose the prefetch latency every iteration.
__device__ __forceinline__ void lds_barrier() {
    asm volatile("s_waitcnt lgkmcnt(0)\n\ts_barrier" ::: "memory");
}

__global__ __launch_bounds__(256, 2)
void conv_mfma_v4(const float* __restrict__ x, const float* __restrict__ w,
                  const float* __restrict__ bias, float* __restrict__ out) {
    __shared__ uint32_t xlds[2][XBUF];
    __shared__ float    ring[RING_DW];

    const int tid  = threadIdx.x;
    const int lane = tid & 63;
    const int wv   = tid >> 6;             // wave -> M-tiles {2wv, 2wv+1}
    const int b    = blockIdx.x >> 3;
    const int h0   = (blockIdx.x & 7) * HB;
    const int r0   = h0 - 3;

    const int nl = lane & 15;
    const int q  = lane >> 4;

    // ---- zero halo cols (cols 0,1,2 and 131,132,133 of both buffers) ----
    for (int i = tid; i < 2 * 6 * XS; i += 256) {
        int bi   = i / (6 * XS);
        int rem  = i - bi * (6 * XS);
        int colh = rem / XS;
        int dwi  = rem - colh * XS;
        int col  = (colh < 3) ? colh : (128 + colh);
        xlds[bi][col * XS + dwi] = 0u;
    }

    // ---- B fragments: Bf[kk][k=8q+j][n=nl] = w_bf16[c, dh=nl, dw] ----
    bf16x8 Bf[14];
#pragma unroll
    for (int kk = 0; kk < 14; kk++) {
        const int dw = kk >> 1, c0 = (kk & 1) * 32;
        bf16x8 f;
#pragma unroll
        for (int j = 0; j < 8; j++) {
            float v = (nl < 7) ? w[(c0 + 8 * q + j) * 49 + nl * 7 + dw] : 0.f;
            uint32_t u = __builtin_bit_cast(uint32_t, v);
            u += 0x7FFFu + ((u >> 16) & 1u);
            f[j] = (short)(u >> 16);
        }
        Bf[kk] = f;
    }

    // ---- staging geometry: cgrp-fastest for bank-safe ds_write ----
    const int cgrp = tid & 7;              // c base = 8*cgrp
    const int colq = tid >> 3;             // 0..31 -> cols 4colq..4colq+3
    const float4* xp = (const float4*)x + (size_t)b * 262144;

    float4 pre[8];
    {   // load row r0
        const bool v = ((unsigned)r0 < 128u);
        const int base = r0 * 32 + colq;
#pragma unroll
        for (int i = 0; i < 8; i++) {
            float4 g = {0.f, 0.f, 0.f, 0.f};
            if (v) g = xp[(8 * cgrp + i) * 4096 + base];
            pre[i] = g;
        }
    }

    // ---- prologue: stage row r0 into buf0, issue loads for row r0+1 ----
    {
        float fa[8][4];
#pragma unroll
        for (int i = 0; i < 8; i++) {
            fa[i][0] = pre[i].x; fa[i][1] = pre[i].y;
            fa[i][2] = pre[i].z; fa[i][3] = pre[i].w;
        }
#pragma unroll
        for (int j = 0; j < 4; j++) {
            uint4 u;
            u.x = pk2bf(fa[0][j], fa[1][j]);
            u.y = pk2bf(fa[2][j], fa[3][j]);
            u.z = pk2bf(fa[4][j], fa[5][j]);
            u.w = pk2bf(fa[6][j], fa[7][j]);
            *(uint4*)&xlds[0][(4 * colq + j + 3) * XS + 4 * cgrp] = u;
        }
        const int rn = r0 + 1;
        const bool v = ((unsigned)rn < 128u);
        const int base = rn * 32 + colq;
#pragma unroll
        for (int i = 0; i < 8; i++) {
            float4 g = {0.f, 0.f, 0.f, 0.f};
            if (v) g = xp[(8 * cgrp + i) * 4096 + base];
            pre[i] = g;
        }
    }
    lds_barrier();

    const float bv = bias[0];
    const int m = nl;

#pragma unroll 1
    for (int it = 0; it < NR; it++) {
        const int r = r0 + it;
        const uint32_t* buf = xlds[it & 1];

        // ---- 1. MFMA: P[r] for this wave's 2 M-tiles ----
        f32x4 acc0 = {0.f, 0.f, 0.f, 0.f};
        f32x4 acc1 = {0.f, 0.f, 0.f, 0.f};
#pragma unroll
        for (int kk = 0; kk < 14; kk++) {
            const int dw  = kk >> 1;
            const int c0h = (kk & 1) * 16;
            const uint32_t* a0 = &buf[(32 * wv + m + dw) * XS + c0h + 4 * q];
            uint4 A0 = *(const uint4*)a0;
            uint4 A1 = *(const uint4*)(a0 + 16 * XS);
            acc0 = __builtin_amdgcn_mfma_f32_16x16x32_bf16(
                       __builtin_bit_cast(bf16x8, A0), Bf[kk], acc0, 0, 0, 0);
            acc1 = __builtin_amdgcn_mfma_f32_16x16x32_bf16(
                       __builtin_bit_cast(bf16x8, A1), Bf[kk], acc1, 0, 0, 0);
        }

        // ---- 2. ring write (C-layout: lane holds n=nl, m=4q+reg) ----
        if (nl < 7) {
            float* dst = &ring[((it & 7) * 7 + nl) * RROW + 32 * wv + 4 * q];
            *(f32x4*)dst = acc0;
            *(f32x4*)(dst + 16) = acc1;
        }

        // ---- 3. stage row r+1 (other buffer), then issue loads row r+2 ----
        if (it + 1 < NR) {
            float fa[8][4];
#pragma unroll
            for (int i = 0; i < 8; i++) {
                fa[i][0] = pre[i].x; fa[i][1] = pre[i].y;
                fa[i][2] = pre[i].z; fa[i][3] = pre[i].w;
            }
            uint32_t* nbuf = xlds[(it + 1) & 1];
#pragma unroll
            for (int j = 0; j < 4; j++) {
                uint4 u;
                u.x = pk2bf(fa[0][j], fa[1][j]);
                u.y = pk2bf(fa[2][j], fa[3][j]);
                u.z = pk2bf(fa[4][j], fa[5][j]);
                u.w = pk2bf(fa[6][j], fa[7][j]);
                *(uint4*)&nbuf[(4 * colq + j + 3) * XS + 4 * cgrp] = u;
            }
            if (it + 2 < NR) {
                const int rn = r + 2;
                const bool v = ((unsigned)rn < 128u);
                const int base = rn * 32 + colq;
#pragma unroll
                for (int i = 0; i < 8; i++) {
                    float4 g = {0.f, 0.f, 0.f, 0.f};
                    if (v) g = xp[(8 * cgrp + i) * 4096 + base];
                    pre[i] = g;
                }
            }
        }

        // ---- 4. single barrier (LDS-only drain; vmcnt stays outstanding) ----
        lds_barrier();

        // ---- 5. drain out-row oh = r-3 (reads P_r written pre-barrier) ----
        if (it >= 6 && tid < 128) {
            const int oh = r - 3;
            float s = bv;
#pragma unroll
            for (int dh = 0; dh < 7; dh++)
                s += ring[(((it - 6 + dh) & 7) * 7 + dh) * RROW + tid];
            out[b * 16384 + oh * 128 + tid] = s;
        }
    }
}

extern "C" void kernel_launch(void* const* d_in, const int* in_sizes, int n_in,
                              void* d_out, int out_size, void* d_ws, size_t ws_size,
                              hipStream_t stream) {
    const float* x    = (const float*)d_in[0];   // (64,64,128,128)
    const float* w    = (const float*)d_in[1];   // (64,7,7)
    const float* bias = (const float*)d_in[2];   // (1,)
    float* out        = (float*)d_out;           // (64,128,128)

    hipLaunchKernelGGL(conv_mfma_v4, dim3(512), dim3(256), 0, stream, x, w, bias, out);
}

// Round 6
// 373.910 us; speedup vs baseline: 1.0190x; 1.0190x over previous
//
#include <hip/hip_runtime.h>
#include <stdint.h>

// ConvolutionN: B=64, C=64, H=W=128, K=7, PAD=3, one output channel, fp32.
// v6 = v5 + the in-band guard on the acc RMW (v5's bug: halo rows r0..r0+2
// contributed to out-rows of the PREVIOUS band, aliasing slots oh+8 that are
// never zeroed before reuse -> rows h0+2..h0+7 were contaminated).
//   - wave-private 8-slot LDS accumulator (slot = oh&7, lane-indexed)
//   - C-split x2 (32 ch/block) -> 1024 blocks (~4/CU), fp32 atomicAdd finalize
//   - 2 rows per iteration -> 11 lgkm-only barriers/block
//   - LDS ~47 KB -> 3 blocks/CU resident

typedef short bf16x8 __attribute__((ext_vector_type(8)));
typedef float f32x4 __attribute__((ext_vector_type(4)));

#define HB    16
#define XS    20             // dwords per col slot: 32ch bf16 = 16 dw + 4 pad
#define XCOLS 134            // cols -3..130 stored at +3
#define XB1   (XCOLS * XS)   // one row = 2680 dw
#define AROW  132            // acc row stride (dw)
#define NSLOT 8

__device__ __forceinline__ uint32_t pk2bf(float a, float b) {
    uint32_t ua = __builtin_bit_cast(uint32_t, a);
    uint32_t ub = __builtin_bit_cast(uint32_t, b);
    ua += 0x7FFFu + ((ua >> 16) & 1u);
    ub += 0x7FFFu + ((ub >> 16) & 1u);
    return (ua >> 16) | (ub & 0xFFFF0000u);
}

// LDS-only barrier: global loads stay in flight (no vmcnt(0) drain).
__device__ __forceinline__ void lds_barrier() {
    asm volatile("s_waitcnt lgkmcnt(0)\n\ts_barrier" ::: "memory");
}

__global__ __launch_bounds__(256, 3)
void conv_v6(const float* __restrict__ x, const float* __restrict__ w,
             const float* __restrict__ bias, float* __restrict__ out) {
    __shared__ uint32_t xlds[2][2 * XB1];      // 42880 B
    __shared__ float    acc[NSLOT * AROW];     // 4224 B

    const int tid  = threadIdx.x;
    const int lane = tid & 63;
    const int wv   = tid >> 6;                 // wave -> ow cols 32wv..32wv+31
    const int bx   = blockIdx.x;
    const int cs   = bx & 1;                   // channel half
    const int band = (bx >> 1) & 7;
    const int b    = bx >> 4;
    const int h0   = band * HB;
    const int r0   = h0 - 3;

    const int nl = lane & 15;
    const int q  = lane >> 4;

    // ---- zero acc + halo cols (cols 0,1,2,131,132,133 of both rows/bufs) ----
    for (int i = tid; i < NSLOT * AROW; i += 256) acc[i] = 0.f;
    for (int i = tid; i < 2 * 2 * 6 * XS; i += 256) {
        int bi   = i / (2 * 6 * XS);
        int rem  = i - bi * (2 * 6 * XS);
        int rs   = rem / (6 * XS);
        int rem2 = rem - rs * (6 * XS);
        int colh = rem2 / XS;
        int dwi  = rem2 - colh * XS;
        int col  = (colh < 3) ? colh : (128 + colh);
        xlds[bi][rs * XB1 + col * XS + dwi] = 0u;
    }

    // ---- B fragments: Bf[dw][k=8q+j][n=nl] = w_bf16[32cs+8q+j, dh=nl, dw] ----
    bf16x8 Bf[7];
#pragma unroll
    for (int kk = 0; kk < 7; kk++) {
        bf16x8 f;
#pragma unroll
        for (int j = 0; j < 8; j++) {
            float v = (nl < 7) ? w[(32 * cs + 8 * q + j) * 49 + nl * 7 + kk] : 0.f;
            uint32_t u = __builtin_bit_cast(uint32_t, v);
            u += 0x7FFFu + ((u >> 16) & 1u);
            f[j] = (short)(u >> 16);
        }
        Bf[kk] = f;
    }

    // ---- staging geometry: thread stages 8 ch x 4 cols of ONE row of the pair
    const int cgrp = tid & 3;                  // ch base 8*cgrp (block-local)
    const int rsel = tid >> 7;                 // which row of the pair
    const int colq = (tid >> 2) & 31;          // col quad 0..31
    const float4* xp4 =
        (const float4*)x + ((size_t)b * 64 + 32 * cs + 8 * cgrp) * 4096;

    float4 pre[8];

    // ---- prologue: pair0 load+stage, pair1 load, barrier ----
    {
        const int r = r0 + rsel;
        const bool v = ((unsigned)r < 128u);
        const int base = r * 32 + colq;
#pragma unroll
        for (int i = 0; i < 8; i++) {
            float4 g = {0.f, 0.f, 0.f, 0.f};
            if (v) g = xp4[i * 4096 + base];
            pre[i] = g;
        }
#pragma unroll
        for (int j = 0; j < 4; j++) {
            float c0 = (&pre[0].x)[j], c1 = (&pre[1].x)[j], c2 = (&pre[2].x)[j],
                  c3 = (&pre[3].x)[j], c4 = (&pre[4].x)[j], c5 = (&pre[5].x)[j],
                  c6 = (&pre[6].x)[j], c7 = (&pre[7].x)[j];
            uint4 u;
            u.x = pk2bf(c0, c1); u.y = pk2bf(c2, c3);
            u.z = pk2bf(c4, c5); u.w = pk2bf(c6, c7);
            *(uint4*)&xlds[0][rsel * XB1 + (4 * colq + j + 3) * XS + 4 * cgrp] = u;
        }
        const int rn = r0 + 2 + rsel;
        const bool vn = ((unsigned)rn < 128u);
        const int basen = rn * 32 + colq;
#pragma unroll
        for (int i = 0; i < 8; i++) {
            float4 g = {0.f, 0.f, 0.f, 0.f};
            if (vn) g = xp4[i * 4096 + basen];
            pre[i] = g;
        }
    }
    lds_barrier();

    const float bv = (cs == 0) ? bias[0] : 0.f;

#pragma unroll 1
    for (int k = 0; k < 11; k++) {
        const uint32_t* buf = xlds[k & 1];

        // ---- MFMA + accumulate both rows of the pair ----
#pragma unroll
        for (int sub = 0; sub < 2; sub++) {
            const int r = r0 + 2 * k + sub;
            f32x4 a0 = {0.f, 0.f, 0.f, 0.f};
            f32x4 a1 = {0.f, 0.f, 0.f, 0.f};
            const uint32_t* rowbuf = buf + sub * XB1;
#pragma unroll
            for (int kk = 0; kk < 7; kk++) {
                const uint32_t* ap = &rowbuf[(32 * wv + nl + kk) * XS + 4 * q];
                uint4 A0 = *(const uint4*)ap;
                uint4 A1 = *(const uint4*)(ap + 16 * XS);
                a0 = __builtin_amdgcn_mfma_f32_16x16x32_bf16(
                         __builtin_bit_cast(bf16x8, A0), Bf[kk], a0, 0, 0, 0);
                a1 = __builtin_amdgcn_mfma_f32_16x16x32_bf16(
                         __builtin_bit_cast(bf16x8, A1), Bf[kk], a1, 0, 0, 0);
            }
            // P[r, ow=32wv+4q+j(+16), dh=nl] -> acc slot oh&7, oh = r+3-nl.
            // GUARD: only in-band oh (out-of-band contributions belong to the
            // neighboring band and would alias slot oh+8 -> v5's bug).
            if (nl < 7) {
                const int oh = r + 3 - nl;
                if ((unsigned)(oh - h0) < (unsigned)HB) {
                    const int s = oh & 7;
                    float* p0 = &acc[s * AROW + 32 * wv + 4 * q];
                    f32x4 c0 = *(f32x4*)p0;
                    f32x4 c1 = *(f32x4*)(p0 + 16);
#pragma unroll
                    for (int j = 0; j < 4; j++) { c0[j] += a0[j]; c1[j] += a1[j]; }
                    *(f32x4*)p0 = c0;
                    *(f32x4*)(p0 + 16) = c1;
                }
            }
        }

        // ---- finalize rows oh = r0+2k-3 (+1): all contributions now in ----
        if (k >= 3) {
            const int oh  = r0 + 2 * k - 3 + (lane >> 5);
            const int col = 32 * wv + (lane & 31);
            float* ap = &acc[(oh & 7) * AROW + col];
            float v = *ap + bv;
            *ap = 0.f;                       // reset before slot reuse (oh+8)
            atomicAdd(&out[(size_t)b * 16384 + oh * 128 + col], v);
        }

        // ---- stage pair k+1 (other buffer), then issue loads pair k+2 ----
        if (k <= 9) {
            uint32_t* nbuf = xlds[(k + 1) & 1];
#pragma unroll
            for (int j = 0; j < 4; j++) {
                float c0 = (&pre[0].x)[j], c1 = (&pre[1].x)[j], c2 = (&pre[2].x)[j],
                      c3 = (&pre[3].x)[j], c4 = (&pre[4].x)[j], c5 = (&pre[5].x)[j],
                      c6 = (&pre[6].x)[j], c7 = (&pre[7].x)[j];
                uint4 u;
                u.x = pk2bf(c0, c1); u.y = pk2bf(c2, c3);
                u.z = pk2bf(c4, c5); u.w = pk2bf(c6, c7);
                *(uint4*)&nbuf[rsel * XB1 + (4 * colq + j + 3) * XS + 4 * cgrp] = u;
            }
            if (k <= 8) {
                const int rn = r0 + 2 * (k + 2) + rsel;
                const bool vn = ((unsigned)rn < 128u);
                const int basen = rn * 32 + colq;
#pragma unroll
                for (int i = 0; i < 8; i++) {
                    float4 g = {0.f, 0.f, 0.f, 0.f};
                    if (vn) g = xp4[i * 4096 + basen];
                    pre[i] = g;
                }
            }
        }

        // ---- one LDS-only barrier per pair ----
        lds_barrier();
    }
}

extern "C" void kernel_launch(void* const* d_in, const int* in_sizes, int n_in,
                              void* d_out, int out_size, void* d_ws, size_t ws_size,
                              hipStream_t stream) {
    const float* x    = (const float*)d_in[0];   // (64,64,128,128)
    const float* w    = (const float*)d_in[1];   // (64,7,7)
    const float* bias = (const float*)d_in[2];   // (1,)
    float* out        = (float*)d_out;           // (64,128,128)

    hipMemsetAsync(d_out, 0, (size_t)out_size * sizeof(float), stream);
    hipLaunchKernelGGL(conv_v6, dim3(1024), dim3(256), 0, stream, x, w, bias, out);
}